// Round 16
// baseline (285.630 us; speedup 1.0000x reference)
//
#include <hip/hip_runtime.h>
#include <stdint.h>

#define N_NODES 16384
#define DIM     256
#define KSEL    8192

// ---------------------------------------------------------------------------
// Exact port of Eigen/Cephes pexp<float> (FMA form) — XLA:CPU's f32 exp.
// All steps RN32. Valid for |x| < 88 (our z range is |z| <= ~4.6).
// ---------------------------------------------------------------------------
__device__ __forceinline__ float eigen_pexp_f32(float _x)
{
    float x = fminf(fmaxf(_x, -88.0f), 88.0f);
    float m = floorf(__fmaf_rn(x, 1.44269504088896341f, 0.5f));
    float r = __fmaf_rn(m, -0.693359375f, x);       // x - m*C1
    r = __fmaf_rn(m, 2.12194440e-4f, r);            // r - m*C2
    float r2 = __fmul_rn(r, r);
    float y = 1.9875691500e-4f;
    y = __fmaf_rn(y, r, 1.3981999507e-3f);
    y = __fmaf_rn(y, r, 8.3334519073e-3f);
    y = __fmaf_rn(y, r, 4.1665795894e-2f);
    y = __fmaf_rn(y, r, 1.6666665459e-1f);
    y = __fmaf_rn(y, r, 5.0000001201e-1f);
    y = __fmaf_rn(y, r2, r);
    y = __fadd_rn(y, 1.0f);
    return ldexpf(y, (int)m);                        // y * 2^m, exact
}

// ---------------------------------------------------------------------------
// K1: XLA:CPU-candidate z: 8-wide AVX2-style row reduction —
//   acc[l] (l=0..7) = sum_{k ≡ l mod 8} fma(x[k],W[k]), ascending k,
// then LLVM vector.reduce.fadd BINARY SHUFFLE TREE (halves-fold):
//   s_l = a_l + a_{l+4};  t_l = s_l + s_{l+2};  dot = t_0 + t_1
//   = ((a0+a4)+(a2+a6)) + ((a1+a5)+(a3+a7))      <- differs from R9's hadd
// z = dot + b;  e = pexp(-z);  s = 1/(1+e)  (XLA logistic expansion);
// top_k: s desc, ties -> LOWER index first.
// ---------------------------------------------------------------------------
__global__ __launch_bounds__(256) void score_kernel(
    const float* __restrict__ x, const float* __restrict__ W,
    const float* __restrict__ b, float* __restrict__ scores,
    unsigned long long* __restrict__ keys)
{
    const int i = blockIdx.x * 256 + threadIdx.x;
    const float* xr = x + (size_t)i * DIM;

    float acc[8];
    #pragma unroll
    for (int l = 0; l < 8; ++l) acc[l] = 0.0f;
    #pragma unroll 4
    for (int it = 0; it < DIM / 8; ++it) {
        #pragma unroll
        for (int l = 0; l < 8; ++l)
            acc[l] = __fmaf_rn(xr[it * 8 + l], W[it * 8 + l], acc[l]);
    }
    // llvm.vector.reduce.fadd tree: fold upper half onto lower, repeatedly.
    const float s0 = __fadd_rn(acc[0], acc[4]);
    const float s1 = __fadd_rn(acc[1], acc[5]);
    const float s2 = __fadd_rn(acc[2], acc[6]);
    const float s3 = __fadd_rn(acc[3], acc[7]);
    const float t0 = __fadd_rn(s0, s2);
    const float t1 = __fadd_rn(s1, s3);
    const float dot = __fadd_rn(t0, t1);
    const float z = __fadd_rn(dot, b[0]);
    const float e = eigen_pexp_f32(-z);
    const float s = __fdiv_rn(1.0f, __fadd_rn(1.0f, e));
    scores[i] = s;
    // s in (0,1): positive-float bits are order-preserving.
    // Low word: larger for smaller index -> ties rank lower index first.
    keys[i] = ((unsigned long long)__float_as_uint(s) << 32)
            | (unsigned long long)(0xFFFFFFFFu - (unsigned)i);
}

// ---------------------------------------------------------------------------
// K2: ranks[i] = #{ j : keys[j] > keys[i] } (tie rule folded into key).
// ---------------------------------------------------------------------------
__global__ __launch_bounds__(256) void rank_kernel(
    const unsigned long long* __restrict__ keys, int* __restrict__ ranks)
{
    __shared__ unsigned long long sk[4096];
    const int j0 = blockIdx.y * 4096;
    for (int t = threadIdx.x; t < 4096; t += 256) sk[t] = keys[j0 + t];
    __syncthreads();

    const int i = blockIdx.x * 256 + threadIdx.x;
    const unsigned long long ki = keys[i];
    int cnt = 0;
    #pragma unroll 8
    for (int j = 0; j < 4096; ++j) cnt += (sk[j] > ki) ? 1 : 0;
    if (cnt) atomicAdd(&ranks[i], cnt);
}

// ---------------------------------------------------------------------------
// K3: scatter top-k: rank < K -> position rank in the sorted output.
// ---------------------------------------------------------------------------
__global__ __launch_bounds__(256) void scatter_kernel(
    const int* __restrict__ ranks, const float* __restrict__ scores,
    int* __restrict__ idxs, float* __restrict__ vs, float* __restrict__ out_idx)
{
    const int i = blockIdx.x * 256 + threadIdx.x;
    const int r = ranks[i];
    if (r < KSEL) {
        idxs[r]    = i;
        vs[r]      = scores[i];
        out_idx[r] = (float)i;
    }
}

// ---------------------------------------------------------------------------
// K4: x_pooled[r,:] = x[idxs[r],:] * vs[r]. One wave per output row.
// ---------------------------------------------------------------------------
__global__ __launch_bounds__(256) void xpool_kernel(
    const float* __restrict__ x, const int* __restrict__ idxs,
    const float* __restrict__ vs, float* __restrict__ outx)
{
    const int wave = (blockIdx.x * 256 + threadIdx.x) >> 6;
    const int lane = threadIdx.x & 63;
    const int row  = idxs[wave];
    const float v  = vs[wave];
    const float4 xv = *reinterpret_cast<const float4*>(x + (size_t)row * DIM + lane * 4);
    float4 o;
    o.x = xv.x * v; o.y = xv.y * v; o.z = xv.z * v; o.w = xv.w * v;
    *reinterpret_cast<float4*>(outx + (size_t)wave * DIM + lane * 4) = o;
}

// ---------------------------------------------------------------------------
// K5: A_pooled[r,c] = (A[idxs[r], idxs[c]])^2. One block per output row:
// stage the 64 KiB source row in LDS (HBM fetch exactly once, coalesced),
// gather columns from LDS, square, coalesced float4 stores.
// ---------------------------------------------------------------------------
__global__ __launch_bounds__(256) void apool_kernel(
    const float* __restrict__ A, const int* __restrict__ idxs,
    float* __restrict__ outA)
{
    __shared__ float row[N_NODES];
    const int r   = blockIdx.x;
    const int src = idxs[r];
    const float* arow = A + (size_t)src * N_NODES;

    for (int t = threadIdx.x; t < N_NODES / 4; t += 256)
        *reinterpret_cast<float4*>(&row[t * 4]) =
            *reinterpret_cast<const float4*>(arow + t * 4);
    __syncthreads();

    float* orow = outA + (size_t)r * KSEL;
    #pragma unroll
    for (int it = 0; it < KSEL / (256 * 4); ++it) {
        const int q = it * 256 + threadIdx.x;
        const int c = q * 4;
        const int4 id4 = *reinterpret_cast<const int4*>(idxs + c);
        float4 o;
        o.x = row[id4.x]; o.y = row[id4.y]; o.z = row[id4.z]; o.w = row[id4.w];
        o.x *= o.x; o.y *= o.y; o.z *= o.z; o.w *= o.w;
        *reinterpret_cast<float4*>(orow + c) = o;
    }
}

// ---------------------------------------------------------------------------
extern "C" void kernel_launch(void* const* d_in, const int* in_sizes, int n_in,
                              void* d_out, int out_size, void* d_ws, size_t ws_size,
                              hipStream_t stream)
{
    const float* A = (const float*)d_in[0];
    const float* x = (const float*)d_in[1];
    const float* W = (const float*)d_in[2];
    const float* b = (const float*)d_in[3];
    (void)in_sizes; (void)n_in; (void)out_size; (void)ws_size;

    char* ws = (char*)d_ws;
    unsigned long long* keys = (unsigned long long*)(ws);           // 128 KiB
    int*    ranks  = (int*)   (ws + 131072);                        //  64 KiB
    float*  scores = (float*) (ws + 196608);                        //  64 KiB
    int*    idxs   = (int*)   (ws + 262144);                        //  32 KiB
    float*  vs     = (float*) (ws + 294912);                        //  32 KiB

    float* outA = (float*)d_out;                                    // (K,K)
    float* outX = outA + (size_t)KSEL * KSEL;                       // (K,D)
    float* outI = outX + (size_t)KSEL * DIM;                        // (K,)

    score_kernel<<<N_NODES / 256, 256, 0, stream>>>(x, W, b, scores, keys);
    hipMemsetAsync(ranks, 0, N_NODES * sizeof(int), stream);
    dim3 rgrid(N_NODES / 256, 4);
    rank_kernel<<<rgrid, 256, 0, stream>>>(keys, ranks);
    scatter_kernel<<<N_NODES / 256, 256, 0, stream>>>(ranks, scores, idxs, vs, outI);
    xpool_kernel<<<KSEL / 4, 256, 0, stream>>>(x, idxs, vs, outX);
    apool_kernel<<<KSEL, 256, 0, stream>>>(A, idxs, outA);
}

// Round 17
// 188.839 us; speedup vs baseline: 1.5126x; 1.5126x over previous
//
#include <hip/hip_runtime.h>
#include <stdint.h>

#define N_NODES 16384
#define DIM     256
#define KSEL    8192

// ---------------------------------------------------------------------------
// Exact port of Eigen/Cephes pexp<float> (FMA form) — XLA:CPU's f32 exp.
// All steps RN32. Valid for |x| < 88 (our z range is |z| <= ~4.6).
// ---------------------------------------------------------------------------
__device__ __forceinline__ float eigen_pexp_f32(float _x)
{
    float x = fminf(fmaxf(_x, -88.0f), 88.0f);
    float m = floorf(__fmaf_rn(x, 1.44269504088896341f, 0.5f));
    float r = __fmaf_rn(m, -0.693359375f, x);       // x - m*C1
    r = __fmaf_rn(m, 2.12194440e-4f, r);            // r - m*C2
    float r2 = __fmul_rn(r, r);
    float y = 1.9875691500e-4f;
    y = __fmaf_rn(y, r, 1.3981999507e-3f);
    y = __fmaf_rn(y, r, 8.3334519073e-3f);
    y = __fmaf_rn(y, r, 4.1665795894e-2f);
    y = __fmaf_rn(y, r, 1.6666665459e-1f);
    y = __fmaf_rn(y, r, 5.0000001201e-1f);
    y = __fmaf_rn(y, r2, r);
    y = __fadd_rn(y, 1.0f);
    return ldexpf(y, (int)m);                        // y * 2^m, exact
}

// ---------------------------------------------------------------------------
// K1: SAME numerics as the passing R16 kernel, remapped 8 lanes/row:
// lane l owns acc chain l (sum over k ≡ l mod 8, ascending, FMA), then the
// LLVM halves-fold tree via __shfl_xor(4,2,1) — each fold computes the
// identical RN32 add (commutative), so keys are bit-identical to R16.
// 131072 threads; coalesced 32B/8-lane-group loads. Also zeroes ranks[].
// ---------------------------------------------------------------------------
__global__ __launch_bounds__(256) void score_kernel(
    const float* __restrict__ x, const float* __restrict__ W,
    const float* __restrict__ b, float* __restrict__ scores,
    unsigned long long* __restrict__ keys, int* __restrict__ ranks)
{
    const int tid = blockIdx.x * 256 + threadIdx.x;
    const int row = tid >> 3;
    const int l   = tid & 7;

    const float* xr = x + (size_t)row * DIM;
    float a = 0.0f;
    #pragma unroll 8
    for (int it = 0; it < DIM / 8; ++it)
        a = __fmaf_rn(xr[it * 8 + l], W[it * 8 + l], a);

    // halves-fold tree: ((a0+a4)+(a2+a6)) + ((a1+a5)+(a3+a7))
    const float s   = __fadd_rn(a, __shfl_xor(a, 4, 64));
    const float t   = __fadd_rn(s, __shfl_xor(s, 2, 64));
    const float dot = __fadd_rn(t, __shfl_xor(t, 1, 64));

    if (l == 0) {
        const float z = __fadd_rn(dot, b[0]);
        const float e = eigen_pexp_f32(-z);
        const float sc = __fdiv_rn(1.0f, __fadd_rn(1.0f, e));
        scores[row] = sc;
        // s in (0,1): positive-float bits order-preserving; low word ~row
        // -> ties rank lower index first.
        keys[row] = ((unsigned long long)__float_as_uint(sc) << 32)
                  | (unsigned long long)(0xFFFFFFFFu - (unsigned)row);
        ranks[row] = 0;
    }
}

// ---------------------------------------------------------------------------
// K2: ranks[i] = #{ j : keys[j] > keys[i] }. 2048-key tiles staged as
// ulonglong2 (ds_read_b128 broadcast, 2 keys/read). Grid (64, 8).
// ---------------------------------------------------------------------------
__global__ __launch_bounds__(256) void rank_kernel(
    const unsigned long long* __restrict__ keys, int* __restrict__ ranks)
{
    __shared__ ulonglong2 sk2[1024];                 // 2048 keys, 16 KiB
    const int j0 = blockIdx.y * 2048;
    for (int t = threadIdx.x; t < 1024; t += 256)
        sk2[t] = reinterpret_cast<const ulonglong2*>(keys)[j0 / 2 + t];
    __syncthreads();

    const int i = blockIdx.x * 256 + threadIdx.x;
    const unsigned long long ki = keys[i];
    int cnt = 0;
    #pragma unroll 8
    for (int j = 0; j < 1024; ++j) {
        const ulonglong2 k2 = sk2[j];
        cnt += (k2.x > ki) ? 1 : 0;
        cnt += (k2.y > ki) ? 1 : 0;
    }
    if (cnt) atomicAdd(&ranks[i], cnt);
}

// ---------------------------------------------------------------------------
// K3: scatter top-k: rank < K -> position rank in the sorted output.
// ---------------------------------------------------------------------------
__global__ __launch_bounds__(256) void scatter_kernel(
    const int* __restrict__ ranks, const float* __restrict__ scores,
    int* __restrict__ idxs, float* __restrict__ vs, float* __restrict__ out_idx)
{
    const int i = blockIdx.x * 256 + threadIdx.x;
    const int r = ranks[i];
    if (r < KSEL) {
        idxs[r]    = i;
        vs[r]      = scores[i];
        out_idx[r] = (float)i;
    }
}

// ---------------------------------------------------------------------------
// K4: x_pooled[r,:] = x[idxs[r],:] * vs[r]. One wave per output row.
// ---------------------------------------------------------------------------
__global__ __launch_bounds__(256) void xpool_kernel(
    const float* __restrict__ x, const int* __restrict__ idxs,
    const float* __restrict__ vs, float* __restrict__ outx)
{
    const int wave = (blockIdx.x * 256 + threadIdx.x) >> 6;
    const int lane = threadIdx.x & 63;
    const int row  = idxs[wave];
    const float v  = vs[wave];
    const float4 xv = *reinterpret_cast<const float4*>(x + (size_t)row * DIM + lane * 4);
    float4 o;
    o.x = xv.x * v; o.y = xv.y * v; o.z = xv.z * v; o.w = xv.w * v;
    *reinterpret_cast<float4*>(outx + (size_t)wave * DIM + lane * 4) = o;
}

// ---------------------------------------------------------------------------
// K5: A_pooled[r,c] = (A[idxs[r], idxs[c]])^2. One block per output row.
// Staging now uses global_load_lds width=16: fire-and-forget async copy,
// 16 outstanding 1 KiB chunks per wave, no VGPR round-trip; __syncthreads
// drains vmcnt before the gather. LDS layout identical to the float4 path
// (linear: wave-uniform base + lane*16B).
// ---------------------------------------------------------------------------
__global__ __launch_bounds__(256) void apool_kernel(
    const float* __restrict__ A, const int* __restrict__ idxs,
    float* __restrict__ outA)
{
    __shared__ float row[N_NODES];
    const int r    = blockIdx.x;
    const int src  = idxs[r];
    const int wid  = threadIdx.x >> 6;
    const int lane = threadIdx.x & 63;
    const float* arow = A + (size_t)src * N_NODES;

    #pragma unroll
    for (int c = 0; c < 16; ++c) {
        const int chunk = wid * 16 + c;               // 64 chunks of 256 floats
        const float* gsrc = arow + chunk * 256 + lane * 4;   // per-lane src
        float* ldst = &row[chunk * 256];                     // wave-uniform dst
        __builtin_amdgcn_global_load_lds(
            (const __attribute__((address_space(1))) void*)gsrc,
            (__attribute__((address_space(3))) void*)ldst,
            16, 0, 0);
    }
    __syncthreads();

    float* orow = outA + (size_t)r * KSEL;
    #pragma unroll
    for (int it = 0; it < KSEL / (256 * 4); ++it) {
        const int q = it * 256 + threadIdx.x;
        const int c = q * 4;
        const int4 id4 = *reinterpret_cast<const int4*>(idxs + c);
        float4 o;
        o.x = row[id4.x]; o.y = row[id4.y]; o.z = row[id4.z]; o.w = row[id4.w];
        o.x *= o.x; o.y *= o.y; o.z *= o.z; o.w *= o.w;
        *reinterpret_cast<float4*>(orow + c) = o;
    }
}

// ---------------------------------------------------------------------------
extern "C" void kernel_launch(void* const* d_in, const int* in_sizes, int n_in,
                              void* d_out, int out_size, void* d_ws, size_t ws_size,
                              hipStream_t stream)
{
    const float* A = (const float*)d_in[0];
    const float* x = (const float*)d_in[1];
    const float* W = (const float*)d_in[2];
    const float* b = (const float*)d_in[3];
    (void)in_sizes; (void)n_in; (void)out_size; (void)ws_size;

    char* ws = (char*)d_ws;
    unsigned long long* keys = (unsigned long long*)(ws);           // 128 KiB
    int*    ranks  = (int*)   (ws + 131072);                        //  64 KiB
    float*  scores = (float*) (ws + 196608);                        //  64 KiB
    int*    idxs   = (int*)   (ws + 262144);                        //  32 KiB
    float*  vs     = (float*) (ws + 294912);                        //  32 KiB

    float* outA = (float*)d_out;                                    // (K,K)
    float* outX = outA + (size_t)KSEL * KSEL;                       // (K,D)
    float* outI = outX + (size_t)KSEL * DIM;                        // (K,)

    score_kernel<<<N_NODES * 8 / 256, 256, 0, stream>>>(x, W, b, scores, keys, ranks);
    dim3 rgrid(N_NODES / 256, 8);
    rank_kernel<<<rgrid, 256, 0, stream>>>(keys, ranks);
    scatter_kernel<<<N_NODES / 256, 256, 0, stream>>>(ranks, scores, idxs, vs, outI);
    xpool_kernel<<<KSEL / 4, 256, 0, stream>>>(x, idxs, vs, outX);
    apool_kernel<<<KSEL, 256, 0, stream>>>(A, idxs, outA);
}